// Round 1
// 6591.590 us; speedup vs baseline: 1.0758x; 1.0758x over previous
//
#include <hip/hip_runtime.h>
#include <stdint.h>

#define DEV static __device__ __forceinline__

// ---- model constants ----
#define BB 32
#define TT 256
#define SAA 512
#define STT 128
#define DD 1024
#define HH 16
#define HDD 64
#define DFFF 4096
#define SS 896   // T+SA+ST
#define LL 6

using bf16x8 = __attribute__((ext_vector_type(8))) short;
using f32x4  = __attribute__((ext_vector_type(4))) float;

DEV uint16_t f2bf(float f){
  uint32_t u = __float_as_uint(f);
  uint32_t r = (u + 0x7fffu + ((u >> 16) & 1u)) >> 16;
  return (uint16_t)r;
}
DEV float bf2f(uint16_t b){ return __uint_as_float(((uint32_t)b) << 16); }

typedef __attribute__((address_space(3))) void lds_vt;
typedef __attribute__((address_space(1))) void glb_vt;

DEV void gl_lds16(const uint16_t* g, uint16_t* l){
  __builtin_amdgcn_global_load_lds((const glb_vt*)g, (lds_vt*)l, 16, 0, 0);
}

// ---------------- generic NT bf16 GEMM, 128x128 tile, BK=64 ----------------
// Modes: 0=PROJ(bf16 out,+bias opt) 1=RESID(x+=g*(acc+b)) 2=GELU(bf16 ff1)
//        5=ADA(fp32 out,+bias) 6=VT(write V^T bf16)
struct GemmP {
  const uint16_t* A; const uint16_t* B; const uint16_t* B1; const uint16_t* B2;
  uint16_t* outB; float* outF; const float* bias; const float* gvec;
  const float* gatep; float* xres;
  long aOuter, aInner, bOuter, bInner;
  int M, N, K, lda, ldb, ldc, segStart, bShift;
};

template<int MODE>
__global__ __launch_bounds__(256, 2)
void gemm_nt(GemmP p){
  __shared__ uint16_t As[8192];
  __shared__ uint16_t Bs[8192];
  const int tid = threadIdx.x;
  const int w = tid >> 6, l = tid & 63;
  const int n0 = blockIdx.x * 128, m0 = blockIdx.y * 128;

  const uint16_t* Ab = p.A;
  const uint16_t* Bb = p.B + (long)n0 * p.ldb;

  const int rloc = l >> 3, ps = l & 7;
  const int kg_st = (ps - rloc) & 7;  // k-group staged by this lane (XOR-rotation swizzle)

  f32x4 acc[4][4];
  const f32x4 z4 = {0.f, 0.f, 0.f, 0.f};
  #pragma unroll
  for (int a = 0; a < 4; ++a)
    #pragma unroll
    for (int b = 0; b < 4; ++b) acc[a][b] = z4;

  const int KT = p.K >> 6;
  for (int kt = 0; kt < KT; ++kt){
    if (kt) __syncthreads();
    const long kbase = ((long)kt << 6) + (kg_st << 3);
    #pragma unroll
    for (int i = 0; i < 4; ++i){
      const int c = (w << 2) + i;
      int ar = m0 + (c << 3) + rloc;
      if (ar >= p.M) ar = p.M - 1;               // M<128 (ada): clamp, discard in epilogue
      gl_lds16(Ab + (long)ar * p.lda + kbase, &As[c << 9]);
      const int br = (c << 3) + rloc;            // B rows always in-range (N mult of 128)
      gl_lds16(Bb + (long)br * p.ldb + kbase, &Bs[c << 9]);
    }
    __syncthreads();                              // drains vmcnt before barrier
    #pragma unroll
    for (int ks = 0; ks < 2; ++ks){
      bf16x8 af[4], bfr[4];
      const int kq = (ks << 2) + (l >> 4);
      #pragma unroll
      for (int mt = 0; mt < 4; ++mt){
        const int r = ((w & 1) << 6) + (mt << 4) + (l & 15);
        af[mt] = *(const bf16x8*)&As[(r << 6) + (((kq + r) & 7) << 3)];
      }
      #pragma unroll
      for (int nt = 0; nt < 4; ++nt){
        const int r = ((w >> 1) << 6) + (nt << 4) + (l & 15);
        bfr[nt] = *(const bf16x8*)&Bs[(r << 6) + (((kq + r) & 7) << 3)];
      }
      #pragma unroll
      for (int mt = 0; mt < 4; ++mt)
        #pragma unroll
        for (int nt = 0; nt < 4; ++nt)
          acc[mt][nt] = __builtin_amdgcn_mfma_f32_16x16x32_bf16(af[mt], bfr[nt], acc[mt][nt], 0, 0, 0);
    }
  }

  const int colb = ((w >> 1) << 6) + (l & 15);
  const int rowb = m0 + ((w & 1) << 6) + ((l >> 4) << 2);
  #pragma unroll
  for (int mt = 0; mt < 4; ++mt){
    #pragma unroll
    for (int nt = 0; nt < 4; ++nt){
      const int col = n0 + colb + (nt << 4);
      const int row0 = rowb + (mt << 4);
      if (MODE == 6){
        // rows are 4 consecutive s within one (b,seg): pack 8B store of V^T
        const int b = row0 >> p.bShift;
        const int s = row0 & ((1 << p.bShift) - 1);
        const int hh = col >> 6, d = col & 63;
        ushort4 hv;
        hv.x = f2bf(acc[mt][nt][0]); hv.y = f2bf(acc[mt][nt][1]);
        hv.z = f2bf(acc[mt][nt][2]); hv.w = f2bf(acc[mt][nt][3]);
        *(ushort4*)(p.outB + ((long)((b << 4) + hh) * 128 + d) * 896 + p.segStart + s) = hv;
        continue;
      }
      #pragma unroll
      for (int e = 0; e < 4; ++e){
        const int row = row0 + e;
        if (row >= p.M) continue;
        float v = acc[mt][nt][e];
        if (MODE == 0){
          if (p.bias) v += p.bias[col];
          p.outB[(long)row * p.ldc + col] = f2bf(v);
        } else if (MODE == 5){
          v += p.bias[col];
          p.outF[(long)row * p.ldc + col] = v;
        } else if (MODE == 1){
          v += p.bias[col];
          const int b = row >> 8;
          const float g = p.gvec[b * 6144 + col];
          p.xres[(long)row * 1024 + col] += g * v;
        } else if (MODE == 2){
          v += p.bias[col];
          const float u = 0.7978845608028654f * (v + 0.044715f * v * v * v);
          v = 0.5f * v * (1.f + tanhf(u));
          p.outB[(long)row * 4096 + col] = f2bf(v);
        }
      }
    }
  }
}

// ---------------- fused flash attention ----------------
// One block per (b,h). 4 waves, each owns 64 Q rows. Online softmax over
// 14 KV tiles of 64 (segments: [0,256) ks, [256,768) ka, [768,896) kt).
// K staged [s][d] and V^T staged [d][s] in LDS via global_load_lds with
// source-side XOR swizzle (8-elem blocks, blk ^= row&7) -> conflict-free
// ds_read_b128 fragments. P goes through a per-wave LDS scratch (no
// cross-wave barrier needed) to convert C-layout -> A-frag layout.
__global__ __launch_bounds__(256, 2)
void k_attn(const uint16_t* __restrict__ qb, const uint16_t* __restrict__ ksb,
            const uint16_t* __restrict__ kab, const uint16_t* __restrict__ ktb,
            const uint16_t* __restrict__ vT, uint16_t* __restrict__ ob,
            const float* __restrict__ gatep){
  __shared__ uint16_t Kl[4096];     // 64 s-rows x 64 d (swizzled blocks)
  __shared__ uint16_t Vl[4096];     // 64 d-rows x 64 s (swizzled blocks)
  __shared__ uint16_t Pl[16384];    // 4 waves x [64 q][64 s] (swizzled)
  const int tid = threadIdx.x;
  const int w = tid >> 6, l = tid & 63;
  const int bh = blockIdx.x, b = bh >> 4, h = bh & 15;
  const int g = l >> 4, c = l & 15;

  // Q fragments: lane holds Q[q = m*16+c][d = ks*32 + g*8 .. +7]
  bf16x8 qf[4][2];
  const uint16_t* qbase = qb + (((long)(b * 256 + w * 64)) << 10) + (h << 6);
  #pragma unroll
  for (int m = 0; m < 4; ++m)
    #pragma unroll
    for (int ks = 0; ks < 2; ++ks)
      qf[m][ks] = *(const bf16x8*)(qbase + (((long)(m * 16 + c)) << 10) + ks * 32 + (g << 3));

  f32x4 acc_o[4][4];
  const f32x4 z4 = {0.f, 0.f, 0.f, 0.f};
  #pragma unroll
  for (int m = 0; m < 4; ++m)
    #pragma unroll
    for (int n = 0; n < 4; ++n) acc_o[m][n] = z4;
  float mstate[4][4], lstate[4][4];
  #pragma unroll
  for (int m = 0; m < 4; ++m)
    #pragma unroll
    for (int r = 0; r < 4; ++r){ mstate[m][r] = -1e30f; lstate[m][r] = 0.f; }

  const float gv = *gatep;
  const float gs = 0.125f / (1.f + __expf(-gv));
  uint16_t* pw = Pl + (w << 12);

  for (int kt = 0; kt < 14; ++kt){
    if (kt) __syncthreads();                  // all waves done with Kl/Vl
    // ---- stage K-tile and V^T-tile (each wave: 16 rows x 2 calls) ----
    #pragma unroll
    for (int j = 0; j < 2; ++j){
      const int rr = (w << 4) + (j << 3) + (l >> 3);   // tile-local row 0..63
      const int s = (kt << 6) + rr;
      const uint16_t* src; long row;
      if (s < 256){ src = ksb; row = (long)b * 256 + s; }
      else if (s < 768){ src = kab; row = (long)b * 512 + (s - 256); }
      else { src = ktb; row = (long)b * 128 + (s - 768); }
      const int blk = (l & 7) ^ (rr & 7);              // source-side swizzle
      gl_lds16(src + (row << 10) + (h << 6) + (blk << 3),
               &Kl[((w << 4) + (j << 3)) << 6]);
      gl_lds16(vT + (long)(bh * 128 + rr) * 896 + (kt << 6) + (blk << 3),
               &Vl[((w << 4) + (j << 3)) << 6]);
    }
    __syncthreads();                          // compiler drains vmcnt here

    // ---- scores: S[q][s] = Q . K^T ----
    f32x4 sacc[4][4];
    #pragma unroll
    for (int m = 0; m < 4; ++m)
      #pragma unroll
      for (int n = 0; n < 4; ++n) sacc[m][n] = z4;
    #pragma unroll
    for (int ks = 0; ks < 2; ++ks){
      bf16x8 kf[4];
      #pragma unroll
      for (int n = 0; n < 4; ++n){
        const int s = (n << 4) + c;
        const int blk = (ks << 2) + g;
        kf[n] = *(const bf16x8*)&Kl[(s << 6) + ((blk ^ (s & 7)) << 3)];
      }
      #pragma unroll
      for (int m = 0; m < 4; ++m)
        #pragma unroll
        for (int n = 0; n < 4; ++n)
          sacc[m][n] = __builtin_amdgcn_mfma_f32_16x16x32_bf16(qf[m][ks], kf[n], sacc[m][n], 0, 0, 0);
    }

    const float tsc = (kt >= 12) ? gs : 0.125f;
    // ---- online softmax; P -> per-wave LDS (bf16, swizzled) ----
    #pragma unroll
    for (int m = 0; m < 4; ++m){
      float nm[4], corr[4], tsum[4];
      #pragma unroll
      for (int r = 0; r < 4; ++r){
        float t = fmaxf(fmaxf(sacc[m][0][r], sacc[m][1][r]),
                        fmaxf(sacc[m][2][r], sacc[m][3][r])) * tsc;
        #pragma unroll
        for (int o = 1; o < 16; o <<= 1) t = fmaxf(t, __shfl_xor(t, o));
        nm[r] = fmaxf(mstate[m][r], t);
        corr[r] = __expf(mstate[m][r] - nm[r]);
        mstate[m][r] = nm[r];
        tsum[r] = 0.f;
      }
      const int q4 = (m << 4) + (g << 2);
      #pragma unroll
      for (int n = 0; n < 4; ++n){
        #pragma unroll
        for (int r = 0; r < 4; ++r){
          const float p = __expf(sacc[m][n][r] * tsc - nm[r]);
          tsum[r] += p;
          const int q = q4 + r;
          const int s = (n << 4) + c;
          pw[(q << 6) + (((s >> 3) ^ (q & 7)) << 3) + (s & 7)] = f2bf(p);
        }
      }
      #pragma unroll
      for (int r = 0; r < 4; ++r){
        float t = tsum[r];
        #pragma unroll
        for (int o = 1; o < 16; o <<= 1) t += __shfl_xor(t, o);
        lstate[m][r] = lstate[m][r] * corr[r] + t;
        #pragma unroll
        for (int n = 0; n < 4; ++n) acc_o[m][n][r] *= corr[r];
      }
    }

    // ---- O += P . V  (A = P from pw, B = V^T rows from Vl) ----
    #pragma unroll
    for (int ks = 0; ks < 2; ++ks){
      bf16x8 pf[4], vf[4];
      #pragma unroll
      for (int m = 0; m < 4; ++m){
        const int q = (m << 4) + c;
        const int blk = (ks << 2) + g;
        pf[m] = *(const bf16x8*)&pw[(q << 6) + ((blk ^ (q & 7)) << 3)];
      }
      #pragma unroll
      for (int n = 0; n < 4; ++n){
        const int d = (n << 4) + c;
        const int blk = (ks << 2) + g;
        vf[n] = *(const bf16x8*)&Vl[(d << 6) + ((blk ^ (d & 7)) << 3)];
      }
      #pragma unroll
      for (int m = 0; m < 4; ++m)
        #pragma unroll
        for (int n = 0; n < 4; ++n)
          acc_o[m][n] = __builtin_amdgcn_mfma_f32_16x16x32_bf16(pf[m], vf[n], acc_o[m][n], 0, 0, 0);
    }
  }

  // ---- epilogue: O / l, store bf16 ----
  uint16_t* obase = ob + (((long)(b * 256 + w * 64)) << 10) + (h << 6);
  #pragma unroll
  for (int m = 0; m < 4; ++m){
    float inv[4];
    #pragma unroll
    for (int r = 0; r < 4; ++r) inv[r] = 1.f / lstate[m][r];
    #pragma unroll
    for (int n = 0; n < 4; ++n)
      #pragma unroll
      for (int r = 0; r < 4; ++r)
        obase[(((long)((m << 4) + (g << 2) + r)) << 10) + (n << 4) + c] =
            f2bf(acc_o[m][n][r] * inv[r]);
  }
}

// ---------------- weight transpose+convert (per layer, one launch) ----------------
struct WtP { const float* src[11]; uint16_t* dst; };

__global__ __launch_bounds__(256) void k_wtrans(WtP p){
  __shared__ uint16_t tile[64][65];
  const int idx = blockIdx.x, tid = threadIdx.x;
  const int tx = tid & 63, ty = tid >> 6;
  int wi, Kw, Nw, k0, n0;
  if (idx < 2048){ wi = idx >> 8; int t = idx & 255; Kw = 1024; Nw = 1024; k0 = (t >> 4) << 6; n0 = (t & 15) << 6; }
  else if (idx < 3072){ wi = 8; int t = idx - 2048; Kw = 1024; Nw = 4096; k0 = (t >> 6) << 6; n0 = (t & 63) << 6; }
  else if (idx < 4096){ wi = 9; int t = idx - 3072; Kw = 4096; Nw = 1024; k0 = (t >> 4) << 6; n0 = (t & 15) << 6; }
  else { wi = 10; int t = idx - 4096; Kw = 1024; Nw = 6144; k0 = (t / 96) << 6; n0 = (t % 96) << 6; }
  long doff;
  if (wi < 8) doff = (long)wi * 1048576;
  else if (wi == 8) doff = 8388608;
  else if (wi == 9) doff = 12582912;
  else doff = 16777216;
  const float* src = p.src[wi];
  uint16_t* dst = p.dst + doff;
  #pragma unroll 4
  for (int i = 0; i < 16; ++i){
    const int row = (i << 2) + ty;
    tile[row][tx] = f2bf(src[(long)(k0 + row) * Nw + n0 + tx]);
  }
  __syncthreads();
  #pragma unroll 4
  for (int i = 0; i < 16; ++i){
    const int row = (i << 2) + ty;
    dst[(long)(n0 + row) * Kw + k0 + tx] = tile[tx][row];
  }
}

// ---------------- small kernels ----------------
__global__ __launch_bounds__(256) void k_f2bf4(const float* __restrict__ s, uint16_t* __restrict__ d, int n4){
  const int i = blockIdx.x * 256 + threadIdx.x;
  if (i < n4){
    const float4 v = ((const float4*)s)[i];
    ushort4 o; o.x = f2bf(v.x); o.y = f2bf(v.y); o.z = f2bf(v.z); o.w = f2bf(v.w);
    ((ushort4*)d)[i] = o;
  }
}

__global__ __launch_bounds__(256) void k_silu4(const float* __restrict__ s, uint16_t* __restrict__ d, int n4){
  const int i = blockIdx.x * 256 + threadIdx.x;
  if (i < n4){
    const float4 v = ((const float4*)s)[i];
    ushort4 o;
    o.x = f2bf(v.x / (1.f + expf(-v.x)));
    o.y = f2bf(v.y / (1.f + expf(-v.y)));
    o.z = f2bf(v.z / (1.f + expf(-v.z)));
    o.w = f2bf(v.w / (1.f + expf(-v.w)));
    ((ushort4*)d)[i] = o;
  }
}

// LN with ada modulation: out_bf16 = ln(x)*(1+mul[b,c]) + add[b,c]
__global__ __launch_bounds__(256) void k_ln(const float* __restrict__ x,
    const float* __restrict__ addv, const float* __restrict__ mulv,
    uint16_t* __restrict__ outb){
  const int row = blockIdx.x, tid = threadIdx.x;
  const float4 xv = ((const float4*)(x + (long)row * 1024))[tid];
  float s = xv.x + xv.y + xv.z + xv.w;
  float q = xv.x*xv.x + xv.y*xv.y + xv.z*xv.z + xv.w*xv.w;
  #pragma unroll
  for (int o = 32; o; o >>= 1){ s += __shfl_down(s, o); q += __shfl_down(q, o); }
  __shared__ float rs[4], rq[4];
  if ((tid & 63) == 0){ rs[tid >> 6] = s; rq[tid >> 6] = q; }
  __syncthreads();
  s = rs[0] + rs[1] + rs[2] + rs[3];
  q = rq[0] + rq[1] + rq[2] + rq[3];
  const float mean = s * (1.f / 1024.f);
  const float var  = q * (1.f / 1024.f) - mean * mean;
  const float inv  = rsqrtf(var + 1e-5f);
  const int b = row >> 8;
  const float4 av = ((const float4*)(addv + (long)b * 6144))[tid];
  const float4 mv = ((const float4*)(mulv + (long)b * 6144))[tid];
  ushort4 o4;
  o4.x = f2bf((xv.x - mean) * inv * (1.f + mv.x) + av.x);
  o4.y = f2bf((xv.y - mean) * inv * (1.f + mv.y) + av.y);
  o4.z = f2bf((xv.z - mean) * inv * (1.f + mv.z) + av.z);
  o4.w = f2bf((xv.w - mean) * inv * (1.f + mv.w) + av.w);
  ((ushort4*)(outb + (long)row * 1024))[tid] = o4;
}

// RMS-norm (per head) + RoPE, in place, on q/ks/ka/kt bf16 buffers
__global__ __launch_bounds__(256) void k_rmsrope(uint16_t* qb, uint16_t* ksb,
    uint16_t* kab, uint16_t* ktb, const float* qn, const float* kn){
  const int row = blockIdx.x, tid = threadIdx.x;
  const int l = tid & 63, wv = tid >> 6;
  uint16_t* buf; const float* wgt; int pos; long grow;
  if (row < 8192)      { buf = qb;  wgt = qn; grow = row;         pos = row & 255; }
  else if (row < 16384){ buf = ksb; wgt = kn; grow = row - 8192;  pos = (int)grow & 255; }
  else if (row < 32768){ buf = kab; wgt = kn; grow = row - 16384; pos = (int)grow & 511; }
  else                 { buf = ktb; wgt = kn; grow = row - 32768; pos = (int)grow & 127; }
  const float wl = wgt[l];
  const float invf = exp2f(-0.41524101186092029f * (float)(l & 31)); // 10000^(-2i/64)
  float c, sn; sincosf((float)pos * invf, &sn, &c);
  const float sgn = (l < 32) ? -1.f : 1.f;
  uint16_t* rbase = buf + grow * 1024;
  #pragma unroll
  for (int hh = 0; hh < 4; ++hh){
    uint16_t* hp = rbase + (((hh << 2) + wv) << 6);
    const float v = bf2f(hp[l]);
    float ss = v * v;
    #pragma unroll
    for (int o = 1; o < 64; o <<= 1) ss += __shfl_xor(ss, o);
    const float y = v * rsqrtf(ss * (1.f / 64.f) + 1e-6f) * wl;
    const float prt = __shfl_xor(y, 32);
    hp[l] = f2bf(y * c + sgn * prt * sn);
  }
}

// final: ln(x)*lnw+lnb @ Wout(1024x3) + bout
__global__ __launch_bounds__(256) void k_final(const float* __restrict__ x,
    const float* __restrict__ lw, const float* __restrict__ lb,
    const float* __restrict__ W3, const float* __restrict__ b3,
    float* __restrict__ out){
  const int row = blockIdx.x, tid = threadIdx.x;
  const float4 xv = ((const float4*)(x + (long)row * 1024))[tid];
  float s = xv.x + xv.y + xv.z + xv.w;
  float q = xv.x*xv.x + xv.y*xv.y + xv.z*xv.z + xv.w*xv.w;
  #pragma unroll
  for (int o = 32; o; o >>= 1){ s += __shfl_down(s, o); q += __shfl_down(q, o); }
  __shared__ float rs[4], rq[4];
  if ((tid & 63) == 0){ rs[tid >> 6] = s; rq[tid >> 6] = q; }
  __syncthreads();
  s = rs[0] + rs[1] + rs[2] + rs[3];
  q = rq[0] + rq[1] + rq[2] + rq[3];
  const float mean = s * (1.f / 1024.f);
  const float inv  = rsqrtf(q * (1.f / 1024.f) - mean * mean + 1e-5f);
  const float4 wv = ((const float4*)lw)[tid];
  const float4 bv = ((const float4*)lb)[tid];
  const int c = tid << 2;
  const float y0 = (xv.x - mean) * inv * wv.x + bv.x;
  const float y1 = (xv.y - mean) * inv * wv.y + bv.y;
  const float y2 = (xv.z - mean) * inv * wv.z + bv.z;
  const float y3 = (xv.w - mean) * inv * wv.w + bv.w;
  float o0 = y0*W3[c*3+0] + y1*W3[(c+1)*3+0] + y2*W3[(c+2)*3+0] + y3*W3[(c+3)*3+0];
  float o1 = y0*W3[c*3+1] + y1*W3[(c+1)*3+1] + y2*W3[(c+2)*3+1] + y3*W3[(c+3)*3+1];
  float o2 = y0*W3[c*3+2] + y1*W3[(c+1)*3+2] + y2*W3[(c+2)*3+2] + y3*W3[(c+3)*3+2];
  #pragma unroll
  for (int o = 32; o; o >>= 1){
    o0 += __shfl_down(o0, o); o1 += __shfl_down(o1, o); o2 += __shfl_down(o2, o);
  }
  __shared__ float r0[4], r1[4], r2[4];
  if ((tid & 63) == 0){ r0[tid>>6] = o0; r1[tid>>6] = o1; r2[tid>>6] = o2; }
  __syncthreads();
  if (tid == 0){
    out[(long)row * 3 + 0] = r0[0]+r0[1]+r0[2]+r0[3] + b3[0];
    out[(long)row * 3 + 1] = r1[0]+r1[1]+r1[2]+r1[3] + b3[1];
    out[(long)row * 3 + 2] = r2[0]+r2[1]+r2[2]+r2[3] + b3[2];
  }
}

// ---------------- host orchestration ----------------
extern "C" void kernel_launch(void* const* d_in, const int* in_sizes, int n_in,
                              void* d_out, int out_size, void* d_ws, size_t ws_size,
                              hipStream_t stream){
  (void)in_sizes; (void)n_in; (void)out_size; (void)ws_size;
  const float* X    = (const float*)d_in[0];
  const float* cond = (const float*)d_in[1];
  const float* adp  = (const float*)d_in[2];
  const float* task = (const float*)d_in[3];
  const float* Wq   = (const float*)d_in[4];
  const float* bq   = (const float*)d_in[5];
  const float* Wks  = (const float*)d_in[6];
  const float* Wvs  = (const float*)d_in[7];
  const float* Wka  = (const float*)d_in[8];
  const float* Wva  = (const float*)d_in[9];
  const float* Wkt  = (const float*)d_in[10];
  const float* Wvt  = (const float*)d_in[11];
  const float* Wo   = (const float*)d_in[12];
  const float* bo   = (const float*)d_in[13];
  const float* qnw  = (const float*)d_in[14];
  const float* knw  = (const float*)d_in[15];
  const float* gate = (const float*)d_in[16];
  const float* Wada = (const float*)d_in[17];
  const float* bada = (const float*)d_in[18];
  const float* W1   = (const float*)d_in[19];
  const float* b1   = (const float*)d_in[20];
  const float* W2   = (const float*)d_in[21];
  const float* b2   = (const float*)d_in[22];
  const float* lnw  = (const float*)d_in[23];
  const float* lnb  = (const float*)d_in[24];
  const float* Wout = (const float*)d_in[25];
  const float* bout = (const float*)d_in[26];
  float* out = (float*)d_out;

  char* base = (char*)d_ws;
  size_t off = 0;
  auto alloc = [&](size_t bytes)->char*{
    char* r = base + off; off += (bytes + 255) & ~(size_t)255; return r;
  };
  float*    x_cur = (float*)   alloc(8192UL * 1024 * 4);
  float*    ada   = (float*)   alloc(32UL * 6144 * 4);
  uint16_t* csilu = (uint16_t*)alloc(32UL * 1024 * 2);
  uint16_t* hb    = (uint16_t*)alloc(8192UL * 1024 * 2);
  uint16_t* qb    = (uint16_t*)alloc(8192UL * 1024 * 2);
  uint16_t* ksb   = (uint16_t*)alloc(8192UL * 1024 * 2);
  uint16_t* kab   = (uint16_t*)alloc(16384UL * 1024 * 2);
  uint16_t* ktb   = (uint16_t*)alloc(4096UL * 1024 * 2);
  uint16_t* adpb  = (uint16_t*)alloc(16384UL * 1024 * 2);
  uint16_t* taskb = (uint16_t*)alloc(4096UL * 1024 * 2);
  uint16_t* vT    = (uint16_t*)alloc(32UL * 16 * 128 * 896 * 2);
  uint16_t* ob    = (uint16_t*)alloc(8192UL * 1024 * 2);
  uint16_t* Wt    = (uint16_t*)alloc(23068672UL * 2);
  uint16_t* ff1   = (uint16_t*)alloc(8192UL * 4096 * 2);

  hipMemcpyAsync(x_cur, X, 8192UL * 1024 * 4, hipMemcpyDeviceToDevice, stream);
  k_f2bf4<<<16384, 256, 0, stream>>>(adp,  adpb,  4194304);
  k_f2bf4<<<4096,  256, 0, stream>>>(task, taskb, 1048576);
  k_silu4<<<32,    256, 0, stream>>>(cond, csilu, 8192);

  for (int i = 0; i < LL; ++i){
    // 1. transpose+convert this layer's weights into Wt
    WtP wp;
    wp.src[0] = Wq  + (long)i * 1048576;
    wp.src[1] = Wks + (long)i * 1048576;
    wp.src[2] = Wvs + (long)i * 1048576;
    wp.src[3] = Wka + (long)i * 1048576;
    wp.src[4] = Wva + (long)i * 1048576;
    wp.src[5] = Wkt + (long)i * 1048576;
    wp.src[6] = Wvt + (long)i * 1048576;
    wp.src[7] = Wo  + (long)i * 1048576;
    wp.src[8] = W1  + (long)i * 4194304;
    wp.src[9] = W2  + (long)i * 4194304;
    wp.src[10]= Wada+ (long)i * 6291456;
    wp.dst = Wt;
    k_wtrans<<<5632, 256, 0, stream>>>(wp);

    GemmP g;
    auto clr = [&](){ g = GemmP{}; g.aOuter=g.aInner=g.bOuter=g.bInner=0; };

    // 2. ada = silu(cond) @ Wada + bada   (M=32 via clamp)
    clr();
    g.A = csilu; g.lda = 1024; g.B = Wt + 16777216; g.ldb = 1024;
    g.M = 32; g.N = 6144; g.K = 1024; g.outF = ada; g.bias = bada + (long)i * 6144; g.ldc = 6144;
    gemm_nt<5><<<dim3(48, 1, 1), 256, 0, stream>>>(g);

    // 3. h = ln(x)*(1+sc1)+s1
    k_ln<<<8192, 256, 0, stream>>>(x_cur, ada + 0, ada + 1024, hb);

    // 4. projections
    clr(); g.A=hb; g.lda=1024; g.B=Wt; g.ldb=1024; g.M=8192; g.N=1024; g.K=1024;
    g.outB=qb; g.bias=bq + (long)i*1024; g.ldc=1024;
    gemm_nt<0><<<dim3(8, 64, 1), 256, 0, stream>>>(g);

    clr(); g.A=hb; g.lda=1024; g.B=Wt+1048576; g.ldb=1024; g.M=8192; g.N=1024; g.K=1024;
    g.outB=ksb; g.bias=nullptr; g.ldc=1024;
    gemm_nt<0><<<dim3(8, 64, 1), 256, 0, stream>>>(g);

    clr(); g.A=hb; g.lda=1024; g.B=Wt+2097152; g.ldb=1024; g.M=8192; g.N=1024; g.K=1024;
    g.outB=vT; g.bShift=8; g.segStart=0;
    gemm_nt<6><<<dim3(8, 64, 1), 256, 0, stream>>>(g);

    clr(); g.A=adpb; g.lda=1024; g.B=Wt+3145728; g.ldb=1024; g.M=16384; g.N=1024; g.K=1024;
    g.outB=kab; g.bias=nullptr; g.ldc=1024;
    gemm_nt<0><<<dim3(8, 128, 1), 256, 0, stream>>>(g);

    clr(); g.A=adpb; g.lda=1024; g.B=Wt+4194304; g.ldb=1024; g.M=16384; g.N=1024; g.K=1024;
    g.outB=vT; g.bShift=9; g.segStart=256;
    gemm_nt<6><<<dim3(8, 128, 1), 256, 0, stream>>>(g);

    clr(); g.A=taskb; g.lda=1024; g.B=Wt+5242880; g.ldb=1024; g.M=4096; g.N=1024; g.K=1024;
    g.outB=ktb; g.bias=nullptr; g.ldc=1024;
    gemm_nt<0><<<dim3(8, 32, 1), 256, 0, stream>>>(g);

    clr(); g.A=taskb; g.lda=1024; g.B=Wt+6291456; g.ldb=1024; g.M=4096; g.N=1024; g.K=1024;
    g.outB=vT; g.bShift=7; g.segStart=768;
    gemm_nt<6><<<dim3(8, 32, 1), 256, 0, stream>>>(g);

    // 5. rms-norm + rope on q / ks / ka / kt
    k_rmsrope<<<36864, 256, 0, stream>>>(qb, ksb, kab, ktb,
                                         qnw + (long)i * 64, knw + (long)i * 64);

    // 6. fused flash attention (one block per (b,h))
    k_attn<<<512, 256, 0, stream>>>(qb, ksb, kab, ktb, vT, ob, gate + i);

    // 7. x += g1 * (o @ Wo + bo)
    clr(); g.A=ob; g.lda=1024; g.B=Wt+7340032; g.ldb=1024; g.M=8192; g.N=1024; g.K=1024;
    g.bias=bo + (long)i*1024; g.gvec=ada + 2048; g.xres=x_cur;
    gemm_nt<1><<<dim3(8, 64, 1), 256, 0, stream>>>(g);

    // 8. h2 = ln(x)*(1+sc2)+s2
    k_ln<<<8192, 256, 0, stream>>>(x_cur, ada + 3072, ada + 4096, hb);

    // 9. ff1 = gelu(h2 @ W1 + b1)
    clr(); g.A=hb; g.lda=1024; g.B=Wt+8388608; g.ldb=1024; g.M=8192; g.N=4096; g.K=1024;
    g.outB=ff1; g.bias=b1 + (long)i*4096;
    gemm_nt<2><<<dim3(32, 64, 1), 256, 0, stream>>>(g);

    // 10. x += g2 * (ff1 @ W2 + b2)
    clr(); g.A=ff1; g.lda=4096; g.B=Wt+12582912; g.ldb=4096; g.M=8192; g.N=1024; g.K=4096;
    g.bias=b2 + (long)i*1024; g.gvec=ada + 5120; g.xres=x_cur;
    gemm_nt<1><<<dim3(8, 64, 1), 256, 0, stream>>>(g);
  }

  k_final<<<8192, 256, 0, stream>>>(x_cur, lnw, lnb, Wout, bout, out);
}

// Round 2
// 6234.478 us; speedup vs baseline: 1.1375x; 1.0573x over previous
//
#include <hip/hip_runtime.h>
#include <stdint.h>

#define DEV static __device__ __forceinline__

// ---- model constants ----
#define BB 32
#define TT 256
#define SAA 512
#define STT 128
#define DD 1024
#define HH 16
#define HDD 64
#define DFFF 4096
#define SS 896   // T+SA+ST
#define LL 6

using bf16x8 = __attribute__((ext_vector_type(8))) short;
using f32x4  = __attribute__((ext_vector_type(4))) float;

DEV uint16_t f2bf(float f){
  uint32_t u = __float_as_uint(f);
  uint32_t r = (u + 0x7fffu + ((u >> 16) & 1u)) >> 16;
  return (uint16_t)r;
}
DEV float bf2f(uint16_t b){ return __uint_as_float(((uint32_t)b) << 16); }

typedef __attribute__((address_space(3))) void lds_vt;
typedef __attribute__((address_space(1))) void glb_vt;

DEV void gl_lds16(const uint16_t* g, uint16_t* l){
  __builtin_amdgcn_global_load_lds((const glb_vt*)g, (lds_vt*)l, 16, 0, 0);
}

#define VMCNT4 asm volatile("s_waitcnt vmcnt(4)" ::: "memory")
#define VMCNT0 asm volatile("s_waitcnt vmcnt(0)" ::: "memory")

// ---------------- generic NT bf16 GEMM, 128x128 tile, BK=64 ----------------
// Modes: 0=PROJ(bf16 out,+bias opt) 1=RESID(x+=g*(acc+b)) 2=GELU(bf16 ff1)
//        5=ADA(fp32 out,+bias) 6=VT(write V^T, s-tiled) 7=per-head QK layout
struct GemmP {
  const uint16_t* A; const uint16_t* B;
  uint16_t* outB; float* outF; const float* bias; const float* gvec;
  float* xres;
  int M, N, K, lda, ldb, ldc, segStart, bShift;
};

template<int MODE>
__global__ __launch_bounds__(256, 2)
void gemm_nt(GemmP p){
  __shared__ uint16_t As[8192];
  __shared__ uint16_t Bs[8192];
  const int tid = threadIdx.x;
  const int w = tid >> 6, l = tid & 63;
  const int n0 = blockIdx.x * 128, m0 = blockIdx.y * 128;

  const uint16_t* Ab = p.A;
  const uint16_t* Bb = p.B + (long)n0 * p.ldb;

  const int rloc = l >> 3, ps = l & 7;
  const int kg_st = (ps - rloc) & 7;  // k-group staged by this lane (XOR-rotation swizzle)

  f32x4 acc[4][4];
  const f32x4 z4 = {0.f, 0.f, 0.f, 0.f};
  #pragma unroll
  for (int a = 0; a < 4; ++a)
    #pragma unroll
    for (int b = 0; b < 4; ++b) acc[a][b] = z4;

  const int KT = p.K >> 6;
  for (int kt = 0; kt < KT; ++kt){
    if (kt) __syncthreads();
    const long kbase = ((long)kt << 6) + (kg_st << 3);
    #pragma unroll
    for (int i = 0; i < 4; ++i){
      const int c = (w << 2) + i;
      int ar = m0 + (c << 3) + rloc;
      if (ar >= p.M) ar = p.M - 1;               // M<128 (ada): clamp, discard in epilogue
      gl_lds16(Ab + (long)ar * p.lda + kbase, &As[c << 9]);
      const int br = (c << 3) + rloc;            // B rows always in-range (N mult of 128)
      gl_lds16(Bb + (long)br * p.ldb + kbase, &Bs[c << 9]);
    }
    __syncthreads();                              // drains vmcnt before barrier
    #pragma unroll
    for (int ks = 0; ks < 2; ++ks){
      bf16x8 af[4], bfr[4];
      const int kq = (ks << 2) + (l >> 4);
      #pragma unroll
      for (int mt = 0; mt < 4; ++mt){
        const int r = ((w & 1) << 6) + (mt << 4) + (l & 15);
        af[mt] = *(const bf16x8*)&As[(r << 6) + (((kq + r) & 7) << 3)];
      }
      #pragma unroll
      for (int nt = 0; nt < 4; ++nt){
        const int r = ((w >> 1) << 6) + (nt << 4) + (l & 15);
        bfr[nt] = *(const bf16x8*)&Bs[(r << 6) + (((kq + r) & 7) << 3)];
      }
      #pragma unroll
      for (int mt = 0; mt < 4; ++mt)
        #pragma unroll
        for (int nt = 0; nt < 4; ++nt)
          acc[mt][nt] = __builtin_amdgcn_mfma_f32_16x16x32_bf16(af[mt], bfr[nt], acc[mt][nt], 0, 0, 0);
    }
  }

  const int colb = ((w >> 1) << 6) + (l & 15);
  const int rowb = m0 + ((w & 1) << 6) + ((l >> 4) << 2);
  #pragma unroll
  for (int mt = 0; mt < 4; ++mt){
    #pragma unroll
    for (int nt = 0; nt < 4; ++nt){
      const int col = n0 + colb + (nt << 4);
      const int row0 = rowb + (mt << 4);
      if (MODE == 6){
        // rows are 4 consecutive s within one (b,seg): pack 8B store of V^T
        // layout: vT[((bh*14 + S/64)*64 + d)*64 + S%64]
        const int b = row0 >> p.bShift;
        const int s = row0 & ((1 << p.bShift) - 1);
        const int S = p.segStart + s;
        const int hh = col >> 6, d = col & 63;
        ushort4 hv;
        hv.x = f2bf(acc[mt][nt][0]); hv.y = f2bf(acc[mt][nt][1]);
        hv.z = f2bf(acc[mt][nt][2]); hv.w = f2bf(acc[mt][nt][3]);
        *(ushort4*)(p.outB +
            ((((long)((b << 4) + hh) * 14 + (S >> 6)) * 64 + d) << 6) + (S & 63)) = hv;
        continue;
      }
      #pragma unroll
      for (int e = 0; e < 4; ++e){
        const int row = row0 + e;
        if (row >= p.M) continue;
        float v = acc[mt][nt][e];
        if (MODE == 0){
          if (p.bias) v += p.bias[col];
          p.outB[(long)row * p.ldc + col] = f2bf(v);
        } else if (MODE == 5){
          v += p.bias[col];
          p.outF[(long)row * p.ldc + col] = v;
        } else if (MODE == 1){
          v += p.bias[col];
          const int b = row >> 8;
          const float g = p.gvec[b * 6144 + col];
          p.xres[(long)row * 1024 + col] += g * v;
        } else if (MODE == 2){
          v += p.bias[col];
          const float u = 0.7978845608028654f * (v + 0.044715f * v * v * v);
          v = 0.5f * v * (1.f + tanhf(u));
          p.outB[(long)row * 4096 + col] = f2bf(v);
        } else if (MODE == 7){
          // per-head layout: out[((b*16+h)*ldc + segStart + s)*64 + d]
          if (p.bias) v += p.bias[col];
          const int b = row >> p.bShift;
          const int s = row & ((1 << p.bShift) - 1);
          const int hh = col >> 6, d = col & 63;
          p.outB[((long)((b << 4) + hh) * p.ldc + p.segStart + s) * 64 + d] = f2bf(v);
        }
      }
    }
  }
}

// ---------------- fused flash attention, v2 ----------------
// One block per (b,h). 4 waves x 64 Q rows. 14 KV tiles of 64.
// qT[bh][256][64], kT[bh][896][64], vT[bh][14][64 d][64 s] — all
// head-contiguous so staging is fully coalesced (8 KB contiguous/tile/buf).
// Double-buffered K/V staging: raw s_barrier + counted vmcnt(4) keeps the
// next tile's global_load_lds in flight across the barriers.
__global__ __launch_bounds__(256, 2)
void k_attn(const uint16_t* __restrict__ qT, const uint16_t* __restrict__ kT,
            const uint16_t* __restrict__ vT, uint16_t* __restrict__ ob,
            const float* __restrict__ gatep){
  __shared__ uint16_t Kl[2][4096];   // [buf][64 s][64 d] swizzled 8-elem blocks
  __shared__ uint16_t Vl[2][4096];   // [buf][64 d][64 s] swizzled
  __shared__ uint16_t Pl[16384];     // 4 waves x [64 q][64 s] swizzled
  const int tid = threadIdx.x;
  const int w = tid >> 6, l = tid & 63;
  const int bh = blockIdx.x, b = bh >> 4, h = bh & 15;
  const int g = l >> 4, c = l & 15;

  const uint16_t* kTb = kT + (long)bh * 57344;
  const uint16_t* vTb = vT + (long)bh * 57344;

  // Q fragments: lane holds Q[q = m*16+c][d = ks*32 + g*8 .. +7]
  bf16x8 qf[4][2];
  const uint16_t* qbase = qT + (((long)bh * 256 + w * 64) << 6);
  #pragma unroll
  for (int m = 0; m < 4; ++m)
    #pragma unroll
    for (int ks = 0; ks < 2; ++ks)
      qf[m][ks] = *(const bf16x8*)(qbase + ((m * 16 + c) << 6) + ks * 32 + (g << 3));

  f32x4 acc_o[4][4];
  const f32x4 z4 = {0.f, 0.f, 0.f, 0.f};
  #pragma unroll
  for (int m = 0; m < 4; ++m)
    #pragma unroll
    for (int n = 0; n < 4; ++n) acc_o[m][n] = z4;
  float mstate[4][4], lstate[4][4];
  #pragma unroll
  for (int m = 0; m < 4; ++m)
    #pragma unroll
    for (int r = 0; r < 4; ++r){ mstate[m][r] = -1e30f; lstate[m][r] = 0.f; }

  const float gv = *gatep;
  const float gs = 0.125f / (1.f + __expf(-gv));
  uint16_t* pw = Pl + (w << 12);

  const int rr0 = w << 4, rl = l >> 3, bsw = l & 7;
  auto STAGE = [&](int kt, int buf){
    #pragma unroll
    for (int j = 0; j < 2; ++j){
      const int rr = rr0 + (j << 3) + rl;
      const int blk = bsw ^ (rr & 7);
      const long goff = (((long)(kt << 6) + rr) << 6) + (blk << 3);
      gl_lds16(kTb + goff, &Kl[buf][(rr0 + (j << 3)) << 6]);
      gl_lds16(vTb + goff, &Vl[buf][(rr0 + (j << 3)) << 6]);
    }
  };

  STAGE(0, 0);
  int cur = 0;
  for (int kt = 0; kt < 14; ++kt){
    if (kt < 13){ STAGE(kt + 1, cur ^ 1); VMCNT4; }
    else { VMCNT0; }
    __builtin_amdgcn_s_barrier();             // tile kt resident in buf cur

    // ---- scores: S[q][s] = Q . K^T ----
    f32x4 sacc[4][4];
    #pragma unroll
    for (int m = 0; m < 4; ++m)
      #pragma unroll
      for (int n = 0; n < 4; ++n) sacc[m][n] = z4;
    #pragma unroll
    for (int ks = 0; ks < 2; ++ks){
      bf16x8 kf[4];
      #pragma unroll
      for (int n = 0; n < 4; ++n){
        const int s = (n << 4) + c;
        const int blk = (ks << 2) + g;
        kf[n] = *(const bf16x8*)&Kl[cur][(s << 6) + ((blk ^ (s & 7)) << 3)];
      }
      #pragma unroll
      for (int m = 0; m < 4; ++m)
        #pragma unroll
        for (int n = 0; n < 4; ++n)
          sacc[m][n] = __builtin_amdgcn_mfma_f32_16x16x32_bf16(qf[m][ks], kf[n], sacc[m][n], 0, 0, 0);
    }

    const float tsc = (kt >= 12) ? gs : 0.125f;
    // ---- online softmax; P -> per-wave LDS (bf16, swizzled) ----
    #pragma unroll
    for (int m = 0; m < 4; ++m){
      float nm[4], corr[4], tsum[4];
      #pragma unroll
      for (int r = 0; r < 4; ++r){
        float t = fmaxf(fmaxf(sacc[m][0][r], sacc[m][1][r]),
                        fmaxf(sacc[m][2][r], sacc[m][3][r])) * tsc;
        #pragma unroll
        for (int o = 1; o < 16; o <<= 1) t = fmaxf(t, __shfl_xor(t, o));
        nm[r] = fmaxf(mstate[m][r], t);
        corr[r] = __expf(mstate[m][r] - nm[r]);
        mstate[m][r] = nm[r];
        tsum[r] = 0.f;
      }
      const int q4 = (m << 4) + (g << 2);
      #pragma unroll
      for (int n = 0; n < 4; ++n){
        #pragma unroll
        for (int r = 0; r < 4; ++r){
          const float p = __expf(sacc[m][n][r] * tsc - nm[r]);
          tsum[r] += p;
          const int q = q4 + r;
          const int s = (n << 4) + c;
          pw[(q << 6) + (((s >> 3) ^ (q & 7)) << 3) + (s & 7)] = f2bf(p);
        }
      }
      #pragma unroll
      for (int r = 0; r < 4; ++r){
        float t = tsum[r];
        #pragma unroll
        for (int o = 1; o < 16; o <<= 1) t += __shfl_xor(t, o);
        lstate[m][r] = lstate[m][r] * corr[r] + t;
        #pragma unroll
        for (int n = 0; n < 4; ++n) acc_o[m][n][r] *= corr[r];
      }
    }

    // ---- O += P . V  (A = P from pw, B = V^T rows from Vl) ----
    #pragma unroll
    for (int ks = 0; ks < 2; ++ks){
      bf16x8 pf[4], vf[4];
      #pragma unroll
      for (int m = 0; m < 4; ++m){
        const int q = (m << 4) + c;
        const int blk = (ks << 2) + g;
        pf[m] = *(const bf16x8*)&pw[(q << 6) + ((blk ^ (q & 7)) << 3)];
      }
      #pragma unroll
      for (int n = 0; n < 4; ++n){
        const int d = (n << 4) + c;
        const int blk = (ks << 2) + g;
        vf[n] = *(const bf16x8*)&Vl[cur][(d << 6) + ((blk ^ (d & 7)) << 3)];
      }
      #pragma unroll
      for (int m = 0; m < 4; ++m)
        #pragma unroll
        for (int n = 0; n < 4; ++n)
          acc_o[m][n] = __builtin_amdgcn_mfma_f32_16x16x32_bf16(pf[m], vf[n], acc_o[m][n], 0, 0, 0);
    }
    __builtin_amdgcn_s_barrier();             // everyone done reading buf cur
    cur ^= 1;
  }

  // ---- epilogue: O / l  -> per-wave LDS -> full-line 128B stores ----
  #pragma unroll
  for (int m = 0; m < 4; ++m){
    float inv[4];
    #pragma unroll
    for (int r = 0; r < 4; ++r) inv[r] = 1.f / lstate[m][r];
    const int q4 = (m << 4) + (g << 2);
    #pragma unroll
    for (int n = 0; n < 4; ++n){
      #pragma unroll
      for (int r = 0; r < 4; ++r){
        const int q = q4 + r;
        const int d = (n << 4) + c;
        pw[(q << 6) + (((d >> 3) ^ (q & 7)) << 3) + (d & 7)] = f2bf(acc_o[m][n][r] * inv[r]);
      }
    }
  }
  #pragma unroll
  for (int i = 0; i < 8; ++i){
    const int q = (i << 3) + rl;
    const bf16x8 vv = *(const bf16x8*)&pw[(q << 6) + ((bsw ^ (q & 7)) << 3)];
    *(bf16x8*)(ob + (((long)(b * 256 + w * 64 + q)) << 10) + (h << 6) + (bsw << 3)) = vv;
  }
}

// ---------------- weight transpose+convert (per layer, one launch) ----------------
struct WtP { const float* src[11]; uint16_t* dst; };

__global__ __launch_bounds__(256) void k_wtrans(WtP p){
  __shared__ uint16_t tile[64][65];
  const int idx = blockIdx.x, tid = threadIdx.x;
  const int tx = tid & 63, ty = tid >> 6;
  int wi, Kw, Nw, k0, n0;
  if (idx < 2048){ wi = idx >> 8; int t = idx & 255; Kw = 1024; Nw = 1024; k0 = (t >> 4) << 6; n0 = (t & 15) << 6; }
  else if (idx < 3072){ wi = 8; int t = idx - 2048; Kw = 1024; Nw = 4096; k0 = (t >> 6) << 6; n0 = (t & 63) << 6; }
  else if (idx < 4096){ wi = 9; int t = idx - 3072; Kw = 4096; Nw = 1024; k0 = (t >> 4) << 6; n0 = (t & 15) << 6; }
  else { wi = 10; int t = idx - 4096; Kw = 1024; Nw = 6144; k0 = (t / 96) << 6; n0 = (t % 96) << 6; }
  long doff;
  if (wi < 8) doff = (long)wi * 1048576;
  else if (wi == 8) doff = 8388608;
  else if (wi == 9) doff = 12582912;
  else doff = 16777216;
  const float* src = p.src[wi];
  uint16_t* dst = p.dst + doff;
  #pragma unroll 4
  for (int i = 0; i < 16; ++i){
    const int row = (i << 2) + ty;
    tile[row][tx] = f2bf(src[(long)(k0 + row) * Nw + n0 + tx]);
  }
  __syncthreads();
  #pragma unroll 4
  for (int i = 0; i < 16; ++i){
    const int row = (i << 2) + ty;
    dst[(long)(n0 + row) * Kw + k0 + tx] = tile[tx][row];
  }
}

// ---------------- small kernels ----------------
__global__ __launch_bounds__(256) void k_f2bf4(const float* __restrict__ s, uint16_t* __restrict__ d, int n4){
  const int i = blockIdx.x * 256 + threadIdx.x;
  if (i < n4){
    const float4 v = ((const float4*)s)[i];
    ushort4 o; o.x = f2bf(v.x); o.y = f2bf(v.y); o.z = f2bf(v.z); o.w = f2bf(v.w);
    ((ushort4*)d)[i] = o;
  }
}

__global__ __launch_bounds__(256) void k_silu4(const float* __restrict__ s, uint16_t* __restrict__ d, int n4){
  const int i = blockIdx.x * 256 + threadIdx.x;
  if (i < n4){
    const float4 v = ((const float4*)s)[i];
    ushort4 o;
    o.x = f2bf(v.x / (1.f + expf(-v.x)));
    o.y = f2bf(v.y / (1.f + expf(-v.y)));
    o.z = f2bf(v.z / (1.f + expf(-v.z)));
    o.w = f2bf(v.w / (1.f + expf(-v.w)));
    ((ushort4*)d)[i] = o;
  }
}

// LN with ada modulation: out_bf16 = ln(x)*(1+mul[b,c]) + add[b,c]
__global__ __launch_bounds__(256) void k_ln(const float* __restrict__ x,
    const float* __restrict__ addv, const float* __restrict__ mulv,
    uint16_t* __restrict__ outb){
  const int row = blockIdx.x, tid = threadIdx.x;
  const float4 xv = ((const float4*)(x + (long)row * 1024))[tid];
  float s = xv.x + xv.y + xv.z + xv.w;
  float q = xv.x*xv.x + xv.y*xv.y + xv.z*xv.z + xv.w*xv.w;
  #pragma unroll
  for (int o = 32; o; o >>= 1){ s += __shfl_down(s, o); q += __shfl_down(q, o); }
  __shared__ float rs[4], rq[4];
  if ((tid & 63) == 0){ rs[tid >> 6] = s; rq[tid >> 6] = q; }
  __syncthreads();
  s = rs[0] + rs[1] + rs[2] + rs[3];
  q = rq[0] + rq[1] + rq[2] + rq[3];
  const float mean = s * (1.f / 1024.f);
  const float var  = q * (1.f / 1024.f) - mean * mean;
  const float inv  = rsqrtf(var + 1e-5f);
  const int b = row >> 8;
  const float4 av = ((const float4*)(addv + (long)b * 6144))[tid];
  const float4 mv = ((const float4*)(mulv + (long)b * 6144))[tid];
  ushort4 o4;
  o4.x = f2bf((xv.x - mean) * inv * (1.f + mv.x) + av.x);
  o4.y = f2bf((xv.y - mean) * inv * (1.f + mv.y) + av.y);
  o4.z = f2bf((xv.z - mean) * inv * (1.f + mv.z) + av.z);
  o4.w = f2bf((xv.w - mean) * inv * (1.f + mv.w) + av.w);
  ((ushort4*)(outb + (long)row * 1024))[tid] = o4;
}

// RMS-norm (per head-row) + RoPE on qT/kT layouts.
// Each wave handles 4 rows sharing one position s (one sincos per thread).
__global__ __launch_bounds__(256) void k_rmsrope(uint16_t* qT, uint16_t* kT,
    const float* qn, const float* kn){
  const int tid = threadIdx.x;
  const int l = tid & 63, wv = tid >> 6;
  uint16_t* buf; int s, seqLen; float wl;
  int v;
  if (blockIdx.x < 8192){
    v = blockIdx.x * 4 + wv;            // [0, 32768): 256 s x 128 bh-groups
    buf = qT; wl = qn[l]; s = v >> 7; seqLen = 256;
  } else {
    v = (blockIdx.x - 8192) * 4 + wv;   // [0, 114688): 896 s x 128 bh-groups
    buf = kT; wl = kn[l]; s = v >> 7; seqLen = 896;
  }
  const int u = v & 127;
  const int pos = (seqLen == 256) ? s : ((s < 256) ? s : (s < 768 ? s - 256 : s - 768));
  const float invf = exp2f(-0.41524101186092029f * (float)(l & 31)); // 10000^(-2i/64)
  float cth, snth; sincosf((float)pos * invf, &snth, &cth);
  const float sgn = (l < 32) ? -1.f : 1.f;
  #pragma unroll
  for (int j = 0; j < 4; ++j){
    uint16_t* hp = buf + (((long)(u * 4 + j) * seqLen + s) << 6);
    const float x = bf2f(hp[l]);
    float ss = x * x;
    #pragma unroll
    for (int o = 1; o < 64; o <<= 1) ss += __shfl_xor(ss, o);
    const float y = x * rsqrtf(ss * (1.f / 64.f) + 1e-6f) * wl;
    const float prt = __shfl_xor(y, 32);
    hp[l] = f2bf(y * cth + sgn * prt * snth);
  }
}

// final: ln(x)*lnw+lnb @ Wout(1024x3) + bout
__global__ __launch_bounds__(256) void k_final(const float* __restrict__ x,
    const float* __restrict__ lw, const float* __restrict__ lb,
    const float* __restrict__ W3, const float* __restrict__ b3,
    float* __restrict__ out){
  const int row = blockIdx.x, tid = threadIdx.x;
  const float4 xv = ((const float4*)(x + (long)row * 1024))[tid];
  float s = xv.x + xv.y + xv.z + xv.w;
  float q = xv.x*xv.x + xv.y*xv.y + xv.z*xv.z + xv.w*xv.w;
  #pragma unroll
  for (int o = 32; o; o >>= 1){ s += __shfl_down(s, o); q += __shfl_down(q, o); }
  __shared__ float rs[4], rq[4];
  if ((tid & 63) == 0){ rs[tid >> 6] = s; rq[tid >> 6] = q; }
  __syncthreads();
  s = rs[0] + rs[1] + rs[2] + rs[3];
  q = rq[0] + rq[1] + rq[2] + rq[3];
  const float mean = s * (1.f / 1024.f);
  const float inv  = rsqrtf(q * (1.f / 1024.f) - mean * mean + 1e-5f);
  const float4 wv = ((const float4*)lw)[tid];
  const float4 bv = ((const float4*)lb)[tid];
  const int c = tid << 2;
  const float y0 = (xv.x - mean) * inv * wv.x + bv.x;
  const float y1 = (xv.y - mean) * inv * wv.y + bv.y;
  const float y2 = (xv.z - mean) * inv * wv.z + bv.z;
  const float y3 = (xv.w - mean) * inv * wv.w + bv.w;
  float o0 = y0*W3[c*3+0] + y1*W3[(c+1)*3+0] + y2*W3[(c+2)*3+0] + y3*W3[(c+3)*3+0];
  float o1 = y0*W3[c*3+1] + y1*W3[(c+1)*3+1] + y2*W3[(c+2)*3+1] + y3*W3[(c+3)*3+1];
  float o2 = y0*W3[c*3+2] + y1*W3[(c+1)*3+2] + y2*W3[(c+2)*3+2] + y3*W3[(c+3)*3+2];
  #pragma unroll
  for (int o = 32; o; o >>= 1){
    o0 += __shfl_down(o0, o); o1 += __shfl_down(o1, o); o2 += __shfl_down(o2, o);
  }
  __shared__ float r0[4], r1[4], r2[4];
  if ((tid & 63) == 0){ r0[tid>>6] = o0; r1[tid>>6] = o1; r2[tid>>6] = o2; }
  __syncthreads();
  if (tid == 0){
    out[(long)row * 3 + 0] = r0[0]+r0[1]+r0[2]+r0[3] + b3[0];
    out[(long)row * 3 + 1] = r1[0]+r1[1]+r1[2]+r1[3] + b3[1];
    out[(long)row * 3 + 2] = r2[0]+r2[1]+r2[2]+r2[3] + b3[2];
  }
}

// ---------------- host orchestration ----------------
extern "C" void kernel_launch(void* const* d_in, const int* in_sizes, int n_in,
                              void* d_out, int out_size, void* d_ws, size_t ws_size,
                              hipStream_t stream){
  (void)in_sizes; (void)n_in; (void)out_size; (void)ws_size;
  const float* X    = (const float*)d_in[0];
  const float* cond = (const float*)d_in[1];
  const float* adp  = (const float*)d_in[2];
  const float* task = (const float*)d_in[3];
  const float* Wq   = (const float*)d_in[4];
  const float* bq   = (const float*)d_in[5];
  const float* Wks  = (const float*)d_in[6];
  const float* Wvs  = (const float*)d_in[7];
  const float* Wka  = (const float*)d_in[8];
  const float* Wva  = (const float*)d_in[9];
  const float* Wkt  = (const float*)d_in[10];
  const float* Wvt  = (const float*)d_in[11];
  const float* Wo   = (const float*)d_in[12];
  const float* bo   = (const float*)d_in[13];
  const float* qnw  = (const float*)d_in[14];
  const float* knw  = (const float*)d_in[15];
  const float* gate = (const float*)d_in[16];
  const float* Wada = (const float*)d_in[17];
  const float* bada = (const float*)d_in[18];
  const float* W1   = (const float*)d_in[19];
  const float* b1   = (const float*)d_in[20];
  const float* W2   = (const float*)d_in[21];
  const float* b2   = (const float*)d_in[22];
  const float* lnw  = (const float*)d_in[23];
  const float* lnb  = (const float*)d_in[24];
  const float* Wout = (const float*)d_in[25];
  const float* bout = (const float*)d_in[26];
  float* out = (float*)d_out;

  char* base = (char*)d_ws;
  size_t off = 0;
  auto alloc = [&](size_t bytes)->char*{
    char* r = base + off; off += (bytes + 255) & ~(size_t)255; return r;
  };
  float*    x_cur = (float*)   alloc(8192UL * 1024 * 4);
  float*    ada   = (float*)   alloc(32UL * 6144 * 4);
  uint16_t* csilu = (uint16_t*)alloc(32UL * 1024 * 2);
  uint16_t* hb    = (uint16_t*)alloc(8192UL * 1024 * 2);
  uint16_t* qTb   = (uint16_t*)alloc(512UL * 256 * 64 * 2);
  uint16_t* kTb   = (uint16_t*)alloc(512UL * 896 * 64 * 2);
  uint16_t* adpb  = (uint16_t*)alloc(16384UL * 1024 * 2);
  uint16_t* taskb = (uint16_t*)alloc(4096UL * 1024 * 2);
  uint16_t* vT    = (uint16_t*)alloc(512UL * 14 * 64 * 64 * 2);
  uint16_t* ob    = (uint16_t*)alloc(8192UL * 1024 * 2);
  uint16_t* Wt    = (uint16_t*)alloc(23068672UL * 2);
  uint16_t* ff1   = (uint16_t*)alloc(8192UL * 4096 * 2);

  hipMemcpyAsync(x_cur, X, 8192UL * 1024 * 4, hipMemcpyDeviceToDevice, stream);
  k_f2bf4<<<16384, 256, 0, stream>>>(adp,  adpb,  4194304);
  k_f2bf4<<<4096,  256, 0, stream>>>(task, taskb, 1048576);
  k_silu4<<<32,    256, 0, stream>>>(cond, csilu, 8192);

  for (int i = 0; i < LL; ++i){
    // 1. transpose+convert this layer's weights into Wt
    WtP wp;
    wp.src[0] = Wq  + (long)i * 1048576;
    wp.src[1] = Wks + (long)i * 1048576;
    wp.src[2] = Wvs + (long)i * 1048576;
    wp.src[3] = Wka + (long)i * 1048576;
    wp.src[4] = Wva + (long)i * 1048576;
    wp.src[5] = Wkt + (long)i * 1048576;
    wp.src[6] = Wvt + (long)i * 1048576;
    wp.src[7] = Wo  + (long)i * 1048576;
    wp.src[8] = W1  + (long)i * 4194304;
    wp.src[9] = W2  + (long)i * 4194304;
    wp.src[10]= Wada+ (long)i * 6291456;
    wp.dst = Wt;
    k_wtrans<<<5632, 256, 0, stream>>>(wp);

    GemmP g;
    auto clr = [&](){ g = GemmP{}; };

    // 2. ada = silu(cond) @ Wada + bada   (M=32 via clamp)
    clr();
    g.A = csilu; g.lda = 1024; g.B = Wt + 16777216; g.ldb = 1024;
    g.M = 32; g.N = 6144; g.K = 1024; g.outF = ada; g.bias = bada + (long)i * 6144; g.ldc = 6144;
    gemm_nt<5><<<dim3(48, 1, 1), 256, 0, stream>>>(g);

    // 3. h = ln(x)*(1+sc1)+s1
    k_ln<<<8192, 256, 0, stream>>>(x_cur, ada + 0, ada + 1024, hb);

    // 4. projections (Q/K to per-head layouts, V to s-tiled V^T)
    clr(); g.A=hb; g.lda=1024; g.B=Wt; g.ldb=1024; g.M=8192; g.N=1024; g.K=1024;
    g.outB=qTb; g.bias=bq + (long)i*1024; g.ldc=256; g.bShift=8; g.segStart=0;
    gemm_nt<7><<<dim3(8, 64, 1), 256, 0, stream>>>(g);

    clr(); g.A=hb; g.lda=1024; g.B=Wt+1048576; g.ldb=1024; g.M=8192; g.N=1024; g.K=1024;
    g.outB=kTb; g.bias=nullptr; g.ldc=896; g.bShift=8; g.segStart=0;
    gemm_nt<7><<<dim3(8, 64, 1), 256, 0, stream>>>(g);

    clr(); g.A=hb; g.lda=1024; g.B=Wt+2097152; g.ldb=1024; g.M=8192; g.N=1024; g.K=1024;
    g.outB=vT; g.bShift=8; g.segStart=0;
    gemm_nt<6><<<dim3(8, 64, 1), 256, 0, stream>>>(g);

    clr(); g.A=adpb; g.lda=1024; g.B=Wt+3145728; g.ldb=1024; g.M=16384; g.N=1024; g.K=1024;
    g.outB=kTb; g.bias=nullptr; g.ldc=896; g.bShift=9; g.segStart=256;
    gemm_nt<7><<<dim3(8, 128, 1), 256, 0, stream>>>(g);

    clr(); g.A=adpb; g.lda=1024; g.B=Wt+4194304; g.ldb=1024; g.M=16384; g.N=1024; g.K=1024;
    g.outB=vT; g.bShift=9; g.segStart=256;
    gemm_nt<6><<<dim3(8, 128, 1), 256, 0, stream>>>(g);

    clr(); g.A=taskb; g.lda=1024; g.B=Wt+5242880; g.ldb=1024; g.M=4096; g.N=1024; g.K=1024;
    g.outB=kTb; g.bias=nullptr; g.ldc=896; g.bShift=7; g.segStart=768;
    gemm_nt<7><<<dim3(8, 32, 1), 256, 0, stream>>>(g);

    clr(); g.A=taskb; g.lda=1024; g.B=Wt+6291456; g.ldb=1024; g.M=4096; g.N=1024; g.K=1024;
    g.outB=vT; g.bShift=7; g.segStart=768;
    gemm_nt<6><<<dim3(8, 32, 1), 256, 0, stream>>>(g);

    // 5. rms-norm + rope on qT / kT
    k_rmsrope<<<36864, 256, 0, stream>>>(qTb, kTb,
                                         qnw + (long)i * 64, knw + (long)i * 64);

    // 6. fused flash attention (one block per (b,h))
    k_attn<<<512, 256, 0, stream>>>(qTb, kTb, vT, ob, gate + i);

    // 7. x += g1 * (o @ Wo + bo)
    clr(); g.A=ob; g.lda=1024; g.B=Wt+7340032; g.ldb=1024; g.M=8192; g.N=1024; g.K=1024;
    g.bias=bo + (long)i*1024; g.gvec=ada + 2048; g.xres=x_cur;
    gemm_nt<1><<<dim3(8, 64, 1), 256, 0, stream>>>(g);

    // 8. h2 = ln(x)*(1+sc2)+s2
    k_ln<<<8192, 256, 0, stream>>>(x_cur, ada + 3072, ada + 4096, hb);

    // 9. ff1 = gelu(h2 @ W1 + b1)
    clr(); g.A=hb; g.lda=1024; g.B=Wt+8388608; g.ldb=1024; g.M=8192; g.N=4096; g.K=1024;
    g.outB=ff1; g.bias=b1 + (long)i*4096;
    gemm_nt<2><<<dim3(32, 64, 1), 256, 0, stream>>>(g);

    // 10. x += g2 * (ff1 @ W2 + b2)
    clr(); g.A=ff1; g.lda=4096; g.B=Wt+12582912; g.ldb=4096; g.M=8192; g.N=1024; g.K=4096;
    g.bias=b2 + (long)i*1024; g.gvec=ada + 5120; g.xres=x_cur;
    gemm_nt<1><<<dim3(8, 64, 1), 256, 0, stream>>>(g);
  }

  k_final<<<8192, 256, 0, stream>>>(x_cur, lnw, lnb, Wout, bout, out);
}